// Round 4
// baseline (839.920 us; speedup 1.0000x reference)
//
#include <hip/hip_runtime.h>

#define N_NODES 100000
#define N_EDGES 1600000
#define D_IN    128
#define D_OUT   64

// Bucket scheme: nodes grouped into buckets of G; per-bucket edge lists with
// fixed capacity CAP (avg fill 3837, multinomial max ~4.2K -> 6144 is safe).
#define G     240
#define NBKT  ((N_NODES + G - 1) / G)          // 417
#define CAP   6144
#define EPB   4096                              // edges per partition block
#define PBLK  ((N_EDGES + EPB - 1) / EPB)       // 391

// ---------------------------------------------------------------------------
// h = x @ W. 128 nodes/block, 256 threads. W staged in LDS (32 KB).
// ---------------------------------------------------------------------------
__global__ __launch_bounds__(256) void gemm_kernel(const float* __restrict__ x,
                                                   const float* __restrict__ W,
                                                   float* __restrict__ h) {
    __shared__ float Wl[D_IN * D_OUT];
    float4* Wl4 = reinterpret_cast<float4*>(Wl);
    {
        const float4* Wg4 = reinterpret_cast<const float4*>(W);
        #pragma unroll
        for (int i = 0; i < (D_IN * D_OUT / 4) / 256; ++i)
            Wl4[threadIdx.x + i * 256] = Wg4[threadIdx.x + i * 256];
    }
    __syncthreads();

    const int t   = threadIdx.x;
    const int fg  = t & 3;
    const int ng  = t >> 2;
    const int n0  = blockIdx.x * 128 + ng * 2;
    const int n1  = n0 + 1;
    const bool v0 = (n0 < N_NODES), v1 = (n1 < N_NODES);

    const float4* xa = reinterpret_cast<const float4*>(x) + (size_t)n0 * (D_IN / 4);
    const float4* xb = reinterpret_cast<const float4*>(x) + (size_t)n1 * (D_IN / 4);

    float4 acc0[4], acc1[4];
    #pragma unroll
    for (int c = 0; c < 4; ++c) {
        acc0[c] = make_float4(0.f, 0.f, 0.f, 0.f);
        acc1[c] = make_float4(0.f, 0.f, 0.f, 0.f);
    }

    #pragma unroll 2
    for (int kk = 0; kk < D_IN / 4; ++kk) {
        const float4 xv0 = v0 ? xa[kk] : make_float4(0.f, 0.f, 0.f, 0.f);
        const float4 xv1 = v1 ? xb[kk] : make_float4(0.f, 0.f, 0.f, 0.f);
        const float xs0[4] = {xv0.x, xv0.y, xv0.z, xv0.w};
        const float xs1[4] = {xv1.x, xv1.y, xv1.z, xv1.w};
        #pragma unroll
        for (int r = 0; r < 4; ++r) {
            const int k = 4 * kk + r;
            const float a0 = xs0[r], a1 = xs1[r];
            #pragma unroll
            for (int c = 0; c < 4; ++c) {
                const float4 w = Wl4[k * 16 + fg * 4 + c];
                acc0[c].x += a0 * w.x; acc0[c].y += a0 * w.y;
                acc0[c].z += a0 * w.z; acc0[c].w += a0 * w.w;
                acc1[c].x += a1 * w.x; acc1[c].y += a1 * w.y;
                acc1[c].z += a1 * w.z; acc1[c].w += a1 * w.w;
            }
        }
    }

    float4* h4 = reinterpret_cast<float4*>(h);
    if (v0) {
        #pragma unroll
        for (int c = 0; c < 4; ++c) h4[(size_t)n0 * 16 + fg * 4 + c] = acc0[c];
    }
    if (v1) {
        #pragma unroll
        for (int c = 0; c < 4; ++c) h4[(size_t)n1 * 16 + fg * 4 + c] = acc1[c];
    }
}

// ---------------------------------------------------------------------------
// Partition edges into NBKT dst-buckets. LDS histogram (LDS atomics) + ONE
// device atomic per (block,bucket) for the global cursor (163K total, vs 3.2M
// per-edge atomics before), LDS restage so global writes are bucket-ordered
// runs. Edge packed to 4B: src (17b) | dst_local (8b) << 17.
// ---------------------------------------------------------------------------
__global__ __launch_bounds__(256) void partition_kernel(const int* __restrict__ ei,
                                                        int* __restrict__ gcur,
                                                        int* __restrict__ ebuf) {
    __shared__ int cnt[512];
    __shared__ int sA[512];       // inclusive scan of cnt
    __shared__ int gbase[512];
    __shared__ int stage[EPB];    // 16 KB

    const int tid = threadIdx.x;
    cnt[tid] = 0; cnt[tid + 256] = 0;
    __syncthreads();

    const int e0   = blockIdx.x * EPB;
    const int ecnt = min(EPB, N_EDGES - e0);

    int pk[16], meta[16];
    #pragma unroll
    for (int i = 0; i < 16; ++i) {
        const int l = tid + i * 256;
        meta[i] = -1;
        if (l < ecnt) {
            const int e   = e0 + l;
            const int src = ei[e];
            const int dst = ei[N_EDGES + e];
            const int b   = dst / G;              // compiler magic-mul
            const int dl  = dst - b * G;
            pk[i] = src | (dl << 17);
            const int r = atomicAdd(&cnt[b], 1);  // LDS atomic
            meta[i] = b | (r << 9);               // b<512 (9b), r<4096 (12b)
        }
    }
    __syncthreads();

    sA[tid] = cnt[tid]; sA[tid + 256] = cnt[tid + 256];
    __syncthreads();
    for (int off = 1; off < 512; off <<= 1) {
        const int a0 = (tid >= off) ? sA[tid - off] : 0;
        const int a1 = sA[tid + 256 - off];
        __syncthreads();
        sA[tid] += a0; sA[tid + 256] += a1;
        __syncthreads();
    }

    // one device atomic per non-empty bucket
    for (int b = tid; b < NBKT; b += 256) {
        const int c = cnt[b];
        if (c > 0) gbase[b] = atomicAdd(&gcur[b], c);
    }

    // restage bucket-sorted in LDS
    #pragma unroll
    for (int i = 0; i < 16; ++i) {
        if (meta[i] >= 0) {
            const int b = meta[i] & 511;
            const int r = meta[i] >> 9;
            stage[(sA[b] - cnt[b]) + r] = pk[i];
        }
    }
    __syncthreads();

    // write runs: consecutive idx -> mostly consecutive global positions
    #pragma unroll
    for (int i = 0; i < 16; ++i) {
        const int idx = tid + i * 256;
        if (idx < ecnt) {
            int lo = 0, hi = 511;                 // first b with sA[b] > idx
            while (lo < hi) { const int mid = (lo + hi) >> 1;
                              if (sA[mid] > idx) hi = mid; else lo = mid + 1; }
            const int b   = lo;
            const int pos = gbase[b] + (idx - (sA[b] - cnt[b]));
            if (pos < CAP) ebuf[(size_t)b * CAP + pos] = stage[idx];
        }
    }
}

// ---------------------------------------------------------------------------
// Accumulate: block = bucket. 240x64 fp32 accumulators in 60 KB LDS
// (2 blocks/CU). Per edge: wave reads h[src] coalesced (256B, L2/L3-served),
// ds_add_f32 into dst-local row. Fused bias+relu epilogue, float4 out.
// ---------------------------------------------------------------------------
__global__ __launch_bounds__(1024) void accumulate_kernel(const float* __restrict__ h,
                                                          const int* __restrict__ gcur,
                                                          const int* __restrict__ ebuf,
                                                          const float* __restrict__ bias,
                                                          float* __restrict__ out) {
    __shared__ float acc[G * D_OUT];   // 61440 B
    const int tid = threadIdx.x;
    for (int i = tid; i < G * D_OUT; i += 1024) acc[i] = 0.f;
    __syncthreads();

    const int b    = blockIdx.x;
    const int cnt  = min(gcur[b], CAP);
    const int wave = tid >> 6;
    const int lane = tid & 63;
    const int* eb  = ebuf + (size_t)b * CAP;

    for (int base = wave * 64; base < cnt; base += 16 * 64) {
        const int m  = min(64, cnt - base);
        const int pk = (lane < m) ? eb[base + lane] : 0;
        for (int j = 0; j < m; ++j) {
            const int v   = __shfl(pk, j, 64);
            const int src = v & 0x1FFFF;
            const int dl  = v >> 17;
            atomicAdd(&acc[dl * D_OUT + lane], h[(size_t)src * D_OUT + lane]);
        }
    }
    __syncthreads();

    const int node0 = b * G;
    const float4* a4 = reinterpret_cast<const float4*>(acc);
    const float4* b4 = reinterpret_cast<const float4*>(bias);
    float4* o4 = reinterpret_cast<float4*>(out);
    for (int i = tid; i < G * (D_OUT / 4); i += 1024) {
        const int dl   = i >> 4;
        const int f4   = i & 15;
        const int node = node0 + dl;
        if (node < N_NODES) {
            float4 a = a4[i];
            const float4 bb = b4[f4];
            a.x = fmaxf(a.x + bb.x, 0.f);
            a.y = fmaxf(a.y + bb.y, 0.f);
            a.z = fmaxf(a.z + bb.z, 0.f);
            a.w = fmaxf(a.w + bb.w, 0.f);
            o4[(size_t)node * 16 + f4] = a;
        }
    }
}

// ---------------------------------------------------------------------------
// Fallback path (atomic scatter) if ws too small
// ---------------------------------------------------------------------------
__global__ void init_bias_kernel(float* __restrict__ out, const float* __restrict__ b) {
    int i = blockIdx.x * blockDim.x + threadIdx.x;
    const int total4 = N_NODES * (D_OUT / 4);
    if (i < total4) {
        int f4 = i & (D_OUT / 4 - 1);
        reinterpret_cast<float4*>(out)[i] = reinterpret_cast<const float4*>(b)[f4];
    }
}

__global__ void scatter_kernel(const float* __restrict__ h, const int* __restrict__ ei,
                               float* __restrict__ out) {
    const long long t = (long long)blockIdx.x * blockDim.x + threadIdx.x;
    const int e = (int)(t >> 6);
    const int f = (int)(t & 63);
    if (e < N_EDGES) {
        atomicAdd(out + (size_t)ei[N_EDGES + e] * D_OUT + f,
                  h[(size_t)ei[e] * D_OUT + f]);
    }
}

__global__ void relu_kernel(float* __restrict__ out) {
    int i = blockIdx.x * blockDim.x + threadIdx.x;
    const int total4 = N_NODES * (D_OUT / 4);
    if (i < total4) {
        float4 v = reinterpret_cast<float4*>(out)[i];
        v.x = fmaxf(v.x, 0.f); v.y = fmaxf(v.y, 0.f);
        v.z = fmaxf(v.z, 0.f); v.w = fmaxf(v.w, 0.f);
        reinterpret_cast<float4*>(out)[i] = v;
    }
}

// ---------------------------------------------------------------------------
extern "C" void kernel_launch(void* const* d_in, const int* in_sizes, int n_in,
                              void* d_out, int out_size, void* d_ws, size_t ws_size,
                              hipStream_t stream) {
    const float* x  = (const float*)d_in[0];
    const int*   ei = (const int*)d_in[1];
    const float* W  = (const float*)d_in[2];
    const float* b  = (const float*)d_in[3];
    float* out = (float*)d_out;
    char*  ws  = (char*)d_ws;

    size_t off = 0;
    auto take = [&](size_t bytes) { size_t p = off; off = (off + bytes + 255) & ~255ULL; return p; };
    const size_t o_h    = take((size_t)N_NODES * D_OUT * sizeof(float));   // 25.6 MB
    const size_t o_gcur = take((size_t)NBKT * sizeof(int));
    const size_t o_ebuf = take((size_t)NBKT * CAP * sizeof(int));          // 10.25 MB
    const size_t needed = off;

    float* h = (float*)(ws + o_h);

    gemm_kernel<<<(N_NODES + 127) / 128, 256, 0, stream>>>(x, W, h);

    if (needed <= ws_size) {
        int* gcur = (int*)(ws + o_gcur);
        int* ebuf = (int*)(ws + o_ebuf);
        hipMemsetAsync(gcur, 0, (size_t)NBKT * sizeof(int), stream);
        partition_kernel<<<PBLK, 256, 0, stream>>>(ei, gcur, ebuf);
        accumulate_kernel<<<NBKT, 1024, 0, stream>>>(h, gcur, ebuf, b, out);
    } else {
        const int total4 = N_NODES * (D_OUT / 4);
        init_bias_kernel<<<(total4 + 255) / 256, 256, 0, stream>>>(out, b);
        const long long threads = (long long)N_EDGES * 64;
        scatter_kernel<<<(int)((threads + 255) / 256), 256, 0, stream>>>(h, ei, out);
        relu_kernel<<<(total4 + 255) / 256, 256, 0, stream>>>(out);
    }
}

// Round 5
// 836.660 us; speedup vs baseline: 1.0039x; 1.0039x over previous
//
#include <hip/hip_runtime.h>

#define N_NODES 100000
#define N_EDGES 1600000
#define D_IN    128
#define D_OUT   64

// Bucket scheme: nodes grouped into buckets of G; per-bucket edge lists with
// fixed capacity CAP (avg fill 3840, sd ~62 -> 6144 is >30 sigma safe).
#define G     240
#define NBKT  ((N_NODES + G - 1) / G)          // 417
#define CAP   6144
#define EPB   4096                              // edges per partition block
#define PBLK  ((N_EDGES + EPB - 1) / EPB)       // 391

// ---------------------------------------------------------------------------
// h = x @ W. 128 nodes/block, 256 threads. W staged in LDS (32 KB).
// ---------------------------------------------------------------------------
__global__ __launch_bounds__(256) void gemm_kernel(const float* __restrict__ x,
                                                   const float* __restrict__ W,
                                                   float* __restrict__ h) {
    __shared__ float Wl[D_IN * D_OUT];
    float4* Wl4 = reinterpret_cast<float4*>(Wl);
    {
        const float4* Wg4 = reinterpret_cast<const float4*>(W);
        #pragma unroll
        for (int i = 0; i < (D_IN * D_OUT / 4) / 256; ++i)
            Wl4[threadIdx.x + i * 256] = Wg4[threadIdx.x + i * 256];
    }
    __syncthreads();

    const int t   = threadIdx.x;
    const int fg  = t & 3;
    const int ng  = t >> 2;
    const int n0  = blockIdx.x * 128 + ng * 2;
    const int n1  = n0 + 1;
    const bool v0 = (n0 < N_NODES), v1 = (n1 < N_NODES);

    const float4* xa = reinterpret_cast<const float4*>(x) + (size_t)n0 * (D_IN / 4);
    const float4* xb = reinterpret_cast<const float4*>(x) + (size_t)n1 * (D_IN / 4);

    float4 acc0[4], acc1[4];
    #pragma unroll
    for (int c = 0; c < 4; ++c) {
        acc0[c] = make_float4(0.f, 0.f, 0.f, 0.f);
        acc1[c] = make_float4(0.f, 0.f, 0.f, 0.f);
    }

    #pragma unroll 2
    for (int kk = 0; kk < D_IN / 4; ++kk) {
        const float4 xv0 = v0 ? xa[kk] : make_float4(0.f, 0.f, 0.f, 0.f);
        const float4 xv1 = v1 ? xb[kk] : make_float4(0.f, 0.f, 0.f, 0.f);
        const float xs0[4] = {xv0.x, xv0.y, xv0.z, xv0.w};
        const float xs1[4] = {xv1.x, xv1.y, xv1.z, xv1.w};
        #pragma unroll
        for (int r = 0; r < 4; ++r) {
            const int k = 4 * kk + r;
            const float a0 = xs0[r], a1 = xs1[r];
            #pragma unroll
            for (int c = 0; c < 4; ++c) {
                const float4 w = Wl4[k * 16 + fg * 4 + c];
                acc0[c].x += a0 * w.x; acc0[c].y += a0 * w.y;
                acc0[c].z += a0 * w.z; acc0[c].w += a0 * w.w;
                acc1[c].x += a1 * w.x; acc1[c].y += a1 * w.y;
                acc1[c].z += a1 * w.z; acc1[c].w += a1 * w.w;
            }
        }
    }

    float4* h4 = reinterpret_cast<float4*>(h);
    if (v0) {
        #pragma unroll
        for (int c = 0; c < 4; ++c) h4[(size_t)n0 * 16 + fg * 4 + c] = acc0[c];
    }
    if (v1) {
        #pragma unroll
        for (int c = 0; c < 4; ++c) h4[(size_t)n1 * 16 + fg * 4 + c] = acc1[c];
    }
}

// ---------------------------------------------------------------------------
// Partition edges into NBKT dst-buckets. LDS histogram + one device atomic
// per (block,bucket); LDS restage so global writes are bucket-ordered runs.
// Edge packed to 4B: src (17b) | dst_local (8b) << 17.
// ---------------------------------------------------------------------------
__global__ __launch_bounds__(256) void partition_kernel(const int* __restrict__ ei,
                                                        int* __restrict__ gcur,
                                                        int* __restrict__ ebuf) {
    __shared__ int cnt[512];
    __shared__ int sA[512];
    __shared__ int gbase[512];
    __shared__ int stage[EPB];

    const int tid = threadIdx.x;
    cnt[tid] = 0; cnt[tid + 256] = 0;
    __syncthreads();

    const int e0   = blockIdx.x * EPB;
    const int ecnt = min(EPB, N_EDGES - e0);

    int pk[16], meta[16];
    #pragma unroll
    for (int i = 0; i < 16; ++i) {
        const int l = tid + i * 256;
        meta[i] = -1;
        if (l < ecnt) {
            const int e   = e0 + l;
            const int src = ei[e];
            const int dst = ei[N_EDGES + e];
            const int b   = dst / G;
            const int dl  = dst - b * G;
            pk[i] = src | (dl << 17);
            const int r = atomicAdd(&cnt[b], 1);
            meta[i] = b | (r << 9);
        }
    }
    __syncthreads();

    sA[tid] = cnt[tid]; sA[tid + 256] = cnt[tid + 256];
    __syncthreads();
    for (int off = 1; off < 512; off <<= 1) {
        const int a0 = (tid >= off) ? sA[tid - off] : 0;
        const int a1 = sA[tid + 256 - off];
        __syncthreads();
        sA[tid] += a0; sA[tid + 256] += a1;
        __syncthreads();
    }

    for (int b = tid; b < NBKT; b += 256) {
        const int c = cnt[b];
        if (c > 0) gbase[b] = atomicAdd(&gcur[b], c);
    }

    #pragma unroll
    for (int i = 0; i < 16; ++i) {
        if (meta[i] >= 0) {
            const int b = meta[i] & 511;
            const int r = meta[i] >> 9;
            stage[(sA[b] - cnt[b]) + r] = pk[i];
        }
    }
    __syncthreads();

    #pragma unroll
    for (int i = 0; i < 16; ++i) {
        const int idx = tid + i * 256;
        if (idx < ecnt) {
            int lo = 0, hi = 511;
            while (lo < hi) { const int mid = (lo + hi) >> 1;
                              if (sA[mid] > idx) hi = mid; else lo = mid + 1; }
            const int b   = lo;
            const int pos = gbase[b] + (idx - (sA[b] - cnt[b]));
            if (pos < CAP) ebuf[(size_t)b * CAP + pos] = stage[idx];
        }
    }
}

// ---------------------------------------------------------------------------
// Accumulate v2: block = bucket, 240x64 fp32 in 60 KB LDS. Inner loop batched
// 8 edges: 8 indep shfls -> 8 indep 256B row loads (one vmcnt drain, MLP=8)
// -> 8 LDS float atomics (lane=feature: bank=lane%32, 2-way = conflict-free).
// Round-4's MLP=1 chain (shfl->load->wait->ds_add per edge) was the 686us
// latency bind.
// ---------------------------------------------------------------------------
__global__ __launch_bounds__(1024) void accumulate_kernel(const float* __restrict__ h,
                                                          const int* __restrict__ gcur,
                                                          const int* __restrict__ ebuf,
                                                          const float* __restrict__ bias,
                                                          float* __restrict__ out) {
    __shared__ float acc[G * D_OUT];   // 61440 B
    const int tid = threadIdx.x;
    for (int i = tid; i < G * D_OUT; i += 1024) acc[i] = 0.f;
    __syncthreads();

    const int b    = blockIdx.x;
    const int cnt  = min(gcur[b], CAP);
    const int wave = tid >> 6;
    const int lane = tid & 63;
    const int* eb  = ebuf + (size_t)b * CAP;

    for (int base = wave * 64; base < cnt; base += 16 * 64) {
        const int m  = min(64, cnt - base);
        const int pk = (lane < m) ? eb[base + lane] : 0;
        int j = 0;
        for (; j + 8 <= m; j += 8) {
            int v[8];
            float f[8];
            #pragma unroll
            for (int t = 0; t < 8; ++t) v[t] = __shfl(pk, j + t, 64);
            #pragma unroll
            for (int t = 0; t < 8; ++t)
                f[t] = h[(size_t)(v[t] & 0x1FFFF) * D_OUT + lane];
            #pragma unroll
            for (int t = 0; t < 8; ++t)
                atomicAdd(&acc[(v[t] >> 17) * D_OUT + lane], f[t]);
        }
        for (; j < m; ++j) {
            const int v = __shfl(pk, j, 64);
            atomicAdd(&acc[(v >> 17) * D_OUT + lane],
                      h[(size_t)(v & 0x1FFFF) * D_OUT + lane]);
        }
    }
    __syncthreads();

    const int node0 = b * G;
    const float4* a4 = reinterpret_cast<const float4*>(acc);
    const float4* b4 = reinterpret_cast<const float4*>(bias);
    float4* o4 = reinterpret_cast<float4*>(out);
    for (int i = tid; i < G * (D_OUT / 4); i += 1024) {
        const int dl   = i >> 4;
        const int f4   = i & 15;
        const int node = node0 + dl;
        if (node < N_NODES) {
            float4 a = a4[i];
            const float4 bb = b4[f4];
            a.x = fmaxf(a.x + bb.x, 0.f);
            a.y = fmaxf(a.y + bb.y, 0.f);
            a.z = fmaxf(a.z + bb.z, 0.f);
            a.w = fmaxf(a.w + bb.w, 0.f);
            o4[(size_t)node * 16 + f4] = a;
        }
    }
}

// ---------------------------------------------------------------------------
// Fallback path (atomic scatter) if ws too small
// ---------------------------------------------------------------------------
__global__ void init_bias_kernel(float* __restrict__ out, const float* __restrict__ b) {
    int i = blockIdx.x * blockDim.x + threadIdx.x;
    const int total4 = N_NODES * (D_OUT / 4);
    if (i < total4) {
        int f4 = i & (D_OUT / 4 - 1);
        reinterpret_cast<float4*>(out)[i] = reinterpret_cast<const float4*>(b)[f4];
    }
}

__global__ void scatter_kernel(const float* __restrict__ h, const int* __restrict__ ei,
                               float* __restrict__ out) {
    const long long t = (long long)blockIdx.x * blockDim.x + threadIdx.x;
    const int e = (int)(t >> 6);
    const int f = (int)(t & 63);
    if (e < N_EDGES) {
        atomicAdd(out + (size_t)ei[N_EDGES + e] * D_OUT + f,
                  h[(size_t)ei[e] * D_OUT + f]);
    }
}

__global__ void relu_kernel(float* __restrict__ out) {
    int i = blockIdx.x * blockDim.x + threadIdx.x;
    const int total4 = N_NODES * (D_OUT / 4);
    if (i < total4) {
        float4 v = reinterpret_cast<float4*>(out)[i];
        v.x = fmaxf(v.x, 0.f); v.y = fmaxf(v.y, 0.f);
        v.z = fmaxf(v.z, 0.f); v.w = fmaxf(v.w, 0.f);
        reinterpret_cast<float4*>(out)[i] = v;
    }
}

// ---------------------------------------------------------------------------
extern "C" void kernel_launch(void* const* d_in, const int* in_sizes, int n_in,
                              void* d_out, int out_size, void* d_ws, size_t ws_size,
                              hipStream_t stream) {
    const float* x  = (const float*)d_in[0];
    const int*   ei = (const int*)d_in[1];
    const float* W  = (const float*)d_in[2];
    const float* b  = (const float*)d_in[3];
    float* out = (float*)d_out;
    char*  ws  = (char*)d_ws;

    size_t off = 0;
    auto take = [&](size_t bytes) { size_t p = off; off = (off + bytes + 255) & ~255ULL; return p; };
    const size_t o_h    = take((size_t)N_NODES * D_OUT * sizeof(float));   // 25.6 MB
    const size_t o_gcur = take((size_t)NBKT * sizeof(int));
    const size_t o_ebuf = take((size_t)NBKT * CAP * sizeof(int));          // 10.25 MB
    const size_t needed = off;

    float* h = (float*)(ws + o_h);

    gemm_kernel<<<(N_NODES + 127) / 128, 256, 0, stream>>>(x, W, h);

    if (needed <= ws_size) {
        int* gcur = (int*)(ws + o_gcur);
        int* ebuf = (int*)(ws + o_ebuf);
        hipMemsetAsync(gcur, 0, (size_t)NBKT * sizeof(int), stream);
        partition_kernel<<<PBLK, 256, 0, stream>>>(ei, gcur, ebuf);
        accumulate_kernel<<<NBKT, 1024, 0, stream>>>(h, gcur, ebuf, b, out);
    } else {
        const int total4 = N_NODES * (D_OUT / 4);
        init_bias_kernel<<<(total4 + 255) / 256, 256, 0, stream>>>(out, b);
        const long long threads = (long long)N_EDGES * 64;
        scatter_kernel<<<(int)((threads + 255) / 256), 256, 0, stream>>>(h, ei, out);
        relu_kernel<<<(total4 + 255) / 256, 256, 0, stream>>>(out);
    }
}

// Round 6
// 229.541 us; speedup vs baseline: 3.6591x; 3.6449x over previous
//
#include <hip/hip_runtime.h>

#define N_NODES 100000
#define N_EDGES 1600000
#define D_IN    128
#define D_OUT   64

// Bucket scheme: nodes grouped into buckets of G; per-bucket edge lists with
// fixed capacity CAP (avg fill 3840, binomial sd ~62 -> 6144 is ~37 sigma).
#define G     240
#define NBKT  ((N_NODES + G - 1) / G)          // 417
#define CAP   6144
#define EPB   4096                              // edges per partition block
#define PBLK  ((N_EDGES + EPB - 1) / EPB)       // 391

// ---------------------------------------------------------------------------
// h = x @ W. 128 nodes/block, 256 threads. W staged in LDS (32 KB).
// ---------------------------------------------------------------------------
__global__ __launch_bounds__(256) void gemm_kernel(const float* __restrict__ x,
                                                   const float* __restrict__ W,
                                                   float* __restrict__ h) {
    __shared__ float Wl[D_IN * D_OUT];
    float4* Wl4 = reinterpret_cast<float4*>(Wl);
    {
        const float4* Wg4 = reinterpret_cast<const float4*>(W);
        #pragma unroll
        for (int i = 0; i < (D_IN * D_OUT / 4) / 256; ++i)
            Wl4[threadIdx.x + i * 256] = Wg4[threadIdx.x + i * 256];
    }
    __syncthreads();

    const int t   = threadIdx.x;
    const int fg  = t & 3;
    const int ng  = t >> 2;
    const int n0  = blockIdx.x * 128 + ng * 2;
    const int n1  = n0 + 1;
    const bool v0 = (n0 < N_NODES), v1 = (n1 < N_NODES);

    const float4* xa = reinterpret_cast<const float4*>(x) + (size_t)n0 * (D_IN / 4);
    const float4* xb = reinterpret_cast<const float4*>(x) + (size_t)n1 * (D_IN / 4);

    float4 acc0[4], acc1[4];
    #pragma unroll
    for (int c = 0; c < 4; ++c) {
        acc0[c] = make_float4(0.f, 0.f, 0.f, 0.f);
        acc1[c] = make_float4(0.f, 0.f, 0.f, 0.f);
    }

    #pragma unroll 2
    for (int kk = 0; kk < D_IN / 4; ++kk) {
        const float4 xv0 = v0 ? xa[kk] : make_float4(0.f, 0.f, 0.f, 0.f);
        const float4 xv1 = v1 ? xb[kk] : make_float4(0.f, 0.f, 0.f, 0.f);
        const float xs0[4] = {xv0.x, xv0.y, xv0.z, xv0.w};
        const float xs1[4] = {xv1.x, xv1.y, xv1.z, xv1.w};
        #pragma unroll
        for (int r = 0; r < 4; ++r) {
            const int k = 4 * kk + r;
            const float a0 = xs0[r], a1 = xs1[r];
            #pragma unroll
            for (int c = 0; c < 4; ++c) {
                const float4 w = Wl4[k * 16 + fg * 4 + c];
                acc0[c].x += a0 * w.x; acc0[c].y += a0 * w.y;
                acc0[c].z += a0 * w.z; acc0[c].w += a0 * w.w;
                acc1[c].x += a1 * w.x; acc1[c].y += a1 * w.y;
                acc1[c].z += a1 * w.z; acc1[c].w += a1 * w.w;
            }
        }
    }

    float4* h4 = reinterpret_cast<float4*>(h);
    if (v0) {
        #pragma unroll
        for (int c = 0; c < 4; ++c) h4[(size_t)n0 * 16 + fg * 4 + c] = acc0[c];
    }
    if (v1) {
        #pragma unroll
        for (int c = 0; c < 4; ++c) h4[(size_t)n1 * 16 + fg * 4 + c] = acc1[c];
    }
}

// ---------------------------------------------------------------------------
// Partition edges into NBKT dst-buckets. LDS histogram + one device atomic
// per (block,bucket); LDS restage so global writes are bucket-ordered runs.
// Edge packed to 4B: src (17b) | dst_local (8b) << 17.
// ---------------------------------------------------------------------------
__global__ __launch_bounds__(256) void partition_kernel(const int* __restrict__ ei,
                                                        int* __restrict__ gcur,
                                                        int* __restrict__ ebuf) {
    __shared__ int cnt[512];
    __shared__ int sA[512];
    __shared__ int gbase[512];
    __shared__ int stage[EPB];

    const int tid = threadIdx.x;
    cnt[tid] = 0; cnt[tid + 256] = 0;
    __syncthreads();

    const int e0   = blockIdx.x * EPB;
    const int ecnt = min(EPB, N_EDGES - e0);

    int pk[16], meta[16];
    #pragma unroll
    for (int i = 0; i < 16; ++i) {
        const int l = tid + i * 256;
        meta[i] = -1;
        if (l < ecnt) {
            const int e   = e0 + l;
            const int src = ei[e];
            const int dst = ei[N_EDGES + e];
            const int b   = dst / G;
            const int dl  = dst - b * G;
            pk[i] = src | (dl << 17);
            const int r = atomicAdd(&cnt[b], 1);
            meta[i] = b | (r << 9);
        }
    }
    __syncthreads();

    sA[tid] = cnt[tid]; sA[tid + 256] = cnt[tid + 256];
    __syncthreads();
    for (int off = 1; off < 512; off <<= 1) {
        const int a0 = (tid >= off) ? sA[tid - off] : 0;
        const int a1 = sA[tid + 256 - off];
        __syncthreads();
        sA[tid] += a0; sA[tid + 256] += a1;
        __syncthreads();
    }

    for (int b = tid; b < NBKT; b += 256) {
        const int c = cnt[b];
        if (c > 0) gbase[b] = atomicAdd(&gcur[b], c);
    }

    #pragma unroll
    for (int i = 0; i < 16; ++i) {
        if (meta[i] >= 0) {
            const int b = meta[i] & 511;
            const int r = meta[i] >> 9;
            stage[(sA[b] - cnt[b]) + r] = pk[i];
        }
    }
    __syncthreads();

    #pragma unroll
    for (int i = 0; i < 16; ++i) {
        const int idx = tid + i * 256;
        if (idx < ecnt) {
            int lo = 0, hi = 511;
            while (lo < hi) { const int mid = (lo + hi) >> 1;
                              if (sA[mid] > idx) hi = mid; else lo = mid + 1; }
            const int b   = lo;
            const int pos = gbase[b] + (idx - (sA[b] - cnt[b]));
            if (pos < CAP) ebuf[(size_t)b * CAP + pos] = stage[idx];
        }
    }
}

// ---------------------------------------------------------------------------
// Accumulate v3: 2 blocks per bucket (512 thr). Load bucket edges into LDS,
// build LOCAL CSR in LDS (hist + scan + reorder), then round-3-gather style:
// wave takes dst rows; lane = (edge-sub 0..3) x (float4 0..15); one load instr
// = 4 rows x 256B = 1KB; 8 rows in flight; REGISTER float4 accumulation;
// shfl_xor reduce; fused bias+relu store. No LDS atomics in the hot loop.
// (Round-4/5's 1-row-per-load + LDS-atomic pattern sat at ~10 G lines/s,
//  676 us; round-3's this-pattern did the same traffic ~5x faster.)
// ---------------------------------------------------------------------------
__global__ __launch_bounds__(512) void accumulate_kernel(const float* __restrict__ h,
                                                         const int* __restrict__ gcur,
                                                         const int* __restrict__ ebuf,
                                                         const float* __restrict__ bias,
                                                         float* __restrict__ out) {
    __shared__ int srt[CAP];        // 24 KB: bucket edges sorted by dst-local
    __shared__ int cnt[256];
    __shared__ int scanb[256];
    __shared__ int start[G + 1];

    const int b   = blockIdx.x >> 1;
    const int p   = blockIdx.x & 1;     // which half of the bucket's rows
    const int tid = threadIdx.x;
    const int ecnt = min(gcur[b], CAP);

    if (tid < 256) cnt[tid] = 0;
    __syncthreads();

    // coalesced load of packed edges + LDS histogram by dst-local
    int pk[8], rr[8];
    #pragma unroll
    for (int i = 0; i < 8; ++i) {
        const int idx = tid + i * 512;
        rr[i] = -1;
        if (idx < ecnt) {
            pk[i] = ebuf[(size_t)b * CAP + idx];
            rr[i] = atomicAdd(&cnt[pk[i] >> 17], 1);
        }
    }
    __syncthreads();

    // exclusive scan of cnt -> start[0..G]
    if (tid < 256) scanb[tid] = cnt[tid];
    __syncthreads();
    for (int off = 1; off < 256; off <<= 1) {
        int v = 0;
        if (tid < 256 && tid >= off) v = scanb[tid - off];
        __syncthreads();
        if (tid < 256) scanb[tid] += v;
        __syncthreads();
    }
    if (tid <= G) start[tid] = (tid == 0) ? 0 : scanb[tid - 1];
    __syncthreads();

    // reorder: srt grouped by dst-local, value = src id
    #pragma unroll
    for (int i = 0; i < 8; ++i) {
        if (rr[i] >= 0) {
            const int dl = pk[i] >> 17;
            srt[start[dl] + rr[i]] = pk[i] & 0x1FFFF;
        }
    }
    __syncthreads();

    // gather: 8 waves, rows p*120 + wave + 8k
    const int wave = tid >> 6;
    const int lane = tid & 63;
    const int sub  = lane >> 4;
    const int f4   = lane & 15;
    const float4* h4 = reinterpret_cast<const float4*>(h);
    const float4 bv  = reinterpret_cast<const float4*>(bias)[f4];
    float4* o4 = reinterpret_cast<float4*>(out);

    const int r0 = p * (G / 2);
    for (int r = r0 + wave; r < r0 + G / 2; r += 8) {
        const int node = b * G + r;
        if (node >= N_NODES) break;
        const int s = start[r];
        const int e = start[r + 1];
        float4 acc = make_float4(0.f, 0.f, 0.f, 0.f);
        int j = s + sub;
        for (; j + 4 < e; j += 8) {
            const int s0 = srt[j];
            const int s1 = srt[j + 4];
            const float4 a = h4[(size_t)s0 * 16 + f4];
            const float4 c = h4[(size_t)s1 * 16 + f4];
            acc.x += a.x + c.x; acc.y += a.y + c.y;
            acc.z += a.z + c.z; acc.w += a.w + c.w;
        }
        if (j < e) {
            const int s0 = srt[j];
            const float4 a = h4[(size_t)s0 * 16 + f4];
            acc.x += a.x; acc.y += a.y; acc.z += a.z; acc.w += a.w;
        }
        #pragma unroll
        for (int m = 16; m <= 32; m <<= 1) {
            acc.x += __shfl_xor(acc.x, m, 64);
            acc.y += __shfl_xor(acc.y, m, 64);
            acc.z += __shfl_xor(acc.z, m, 64);
            acc.w += __shfl_xor(acc.w, m, 64);
        }
        if (sub == 0) {
            float4 o;
            o.x = fmaxf(acc.x + bv.x, 0.f);
            o.y = fmaxf(acc.y + bv.y, 0.f);
            o.z = fmaxf(acc.z + bv.z, 0.f);
            o.w = fmaxf(acc.w + bv.w, 0.f);
            o4[(size_t)node * 16 + f4] = o;
        }
    }
}

// ---------------------------------------------------------------------------
// Fallback path (atomic scatter) if ws too small
// ---------------------------------------------------------------------------
__global__ void init_bias_kernel(float* __restrict__ out, const float* __restrict__ b) {
    int i = blockIdx.x * blockDim.x + threadIdx.x;
    const int total4 = N_NODES * (D_OUT / 4);
    if (i < total4) {
        int f4 = i & (D_OUT / 4 - 1);
        reinterpret_cast<float4*>(out)[i] = reinterpret_cast<const float4*>(b)[f4];
    }
}

__global__ void scatter_kernel(const float* __restrict__ h, const int* __restrict__ ei,
                               float* __restrict__ out) {
    const long long t = (long long)blockIdx.x * blockDim.x + threadIdx.x;
    const int e = (int)(t >> 6);
    const int f = (int)(t & 63);
    if (e < N_EDGES) {
        atomicAdd(out + (size_t)ei[N_EDGES + e] * D_OUT + f,
                  h[(size_t)ei[e] * D_OUT + f]);
    }
}

__global__ void relu_kernel(float* __restrict__ out) {
    int i = blockIdx.x * blockDim.x + threadIdx.x;
    const int total4 = N_NODES * (D_OUT / 4);
    if (i < total4) {
        float4 v = reinterpret_cast<float4*>(out)[i];
        v.x = fmaxf(v.x, 0.f); v.y = fmaxf(v.y, 0.f);
        v.z = fmaxf(v.z, 0.f); v.w = fmaxf(v.w, 0.f);
        reinterpret_cast<float4*>(out)[i] = v;
    }
}

// ---------------------------------------------------------------------------
extern "C" void kernel_launch(void* const* d_in, const int* in_sizes, int n_in,
                              void* d_out, int out_size, void* d_ws, size_t ws_size,
                              hipStream_t stream) {
    const float* x  = (const float*)d_in[0];
    const int*   ei = (const int*)d_in[1];
    const float* W  = (const float*)d_in[2];
    const float* b  = (const float*)d_in[3];
    float* out = (float*)d_out;
    char*  ws  = (char*)d_ws;

    size_t off = 0;
    auto take = [&](size_t bytes) { size_t p = off; off = (off + bytes + 255) & ~255ULL; return p; };
    const size_t o_h    = take((size_t)N_NODES * D_OUT * sizeof(float));   // 25.6 MB
    const size_t o_gcur = take((size_t)NBKT * sizeof(int));
    const size_t o_ebuf = take((size_t)NBKT * CAP * sizeof(int));          // 10.25 MB
    const size_t needed = off;

    float* h = (float*)(ws + o_h);

    gemm_kernel<<<(N_NODES + 127) / 128, 256, 0, stream>>>(x, W, h);

    if (needed <= ws_size) {
        int* gcur = (int*)(ws + o_gcur);
        int* ebuf = (int*)(ws + o_ebuf);
        hipMemsetAsync(gcur, 0, (size_t)NBKT * sizeof(int), stream);
        partition_kernel<<<PBLK, 256, 0, stream>>>(ei, gcur, ebuf);
        accumulate_kernel<<<NBKT * 2, 512, 0, stream>>>(h, gcur, ebuf, b, out);
    } else {
        const int total4 = N_NODES * (D_OUT / 4);
        init_bias_kernel<<<(total4 + 255) / 256, 256, 0, stream>>>(out, b);
        const long long threads = (long long)N_EDGES * 64;
        scatter_kernel<<<(int)((threads + 255) / 256), 256, 0, stream>>>(h, ei, out);
        relu_kernel<<<(total4 + 255) / 256, 256, 0, stream>>>(out);
    }
}

// Round 7
// 191.696 us; speedup vs baseline: 4.3815x; 1.1974x over previous
//
#include <hip/hip_runtime.h>

#define N_NODES 100000
#define N_EDGES 1600000
#define D_IN    128
#define D_OUT   64

// Bucket scheme: nodes grouped into buckets of G; per-bucket edge lists with
// fixed capacity CAP (avg fill 3840, binomial sd ~62 -> 6144 is ~37 sigma).
#define G     240
#define NBKT  ((N_NODES + G - 1) / G)          // 417
#define CAP   6144
#define EPB   4096                              // edges per partition block
#define PBLK  ((N_EDGES + EPB - 1) / EPB)       // 391

// fp32 <-> bf16 helpers (RNE; values are finite, no NaN path needed)
__device__ __forceinline__ unsigned short f2bf(float f) {
    union { float f; unsigned u; } v; v.f = f;
    const unsigned r = v.u + 0x7FFFu + ((v.u >> 16) & 1u);
    return (unsigned short)(r >> 16);
}
__device__ __forceinline__ float bf2f(unsigned short s) {
    union { unsigned u; float f; } v; v.u = ((unsigned)s) << 16;
    return v.f;
}

// ---------------------------------------------------------------------------
// h = x @ W (h stored as bf16: halves h write here and all gather reads).
// 128 nodes/block, 256 threads. W staged in LDS (32 KB).
// ---------------------------------------------------------------------------
__global__ __launch_bounds__(256) void gemm_kernel(const float* __restrict__ x,
                                                   const float* __restrict__ W,
                                                   unsigned short* __restrict__ hb) {
    __shared__ float Wl[D_IN * D_OUT];
    float4* Wl4 = reinterpret_cast<float4*>(Wl);
    {
        const float4* Wg4 = reinterpret_cast<const float4*>(W);
        #pragma unroll
        for (int i = 0; i < (D_IN * D_OUT / 4) / 256; ++i)
            Wl4[threadIdx.x + i * 256] = Wg4[threadIdx.x + i * 256];
    }
    __syncthreads();

    const int t   = threadIdx.x;
    const int fg  = t & 3;
    const int ng  = t >> 2;
    const int n0  = blockIdx.x * 128 + ng * 2;
    const int n1  = n0 + 1;
    const bool v0 = (n0 < N_NODES), v1 = (n1 < N_NODES);

    const float4* xa = reinterpret_cast<const float4*>(x) + (size_t)n0 * (D_IN / 4);
    const float4* xb = reinterpret_cast<const float4*>(x) + (size_t)n1 * (D_IN / 4);

    float4 acc0[4], acc1[4];
    #pragma unroll
    for (int c = 0; c < 4; ++c) {
        acc0[c] = make_float4(0.f, 0.f, 0.f, 0.f);
        acc1[c] = make_float4(0.f, 0.f, 0.f, 0.f);
    }

    #pragma unroll 2
    for (int kk = 0; kk < D_IN / 4; ++kk) {
        const float4 xv0 = v0 ? xa[kk] : make_float4(0.f, 0.f, 0.f, 0.f);
        const float4 xv1 = v1 ? xb[kk] : make_float4(0.f, 0.f, 0.f, 0.f);
        const float xs0[4] = {xv0.x, xv0.y, xv0.z, xv0.w};
        const float xs1[4] = {xv1.x, xv1.y, xv1.z, xv1.w};
        #pragma unroll
        for (int r = 0; r < 4; ++r) {
            const int k = 4 * kk + r;
            const float a0 = xs0[r], a1 = xs1[r];
            #pragma unroll
            for (int c = 0; c < 4; ++c) {
                const float4 w = Wl4[k * 16 + fg * 4 + c];
                acc0[c].x += a0 * w.x; acc0[c].y += a0 * w.y;
                acc0[c].z += a0 * w.z; acc0[c].w += a0 * w.w;
                acc1[c].x += a1 * w.x; acc1[c].y += a1 * w.y;
                acc1[c].z += a1 * w.z; acc1[c].w += a1 * w.w;
            }
        }
    }

    ushort4* h4 = reinterpret_cast<ushort4*>(hb);
    if (v0) {
        #pragma unroll
        for (int c = 0; c < 4; ++c) {
            ushort4 hv;
            hv.x = f2bf(acc0[c].x); hv.y = f2bf(acc0[c].y);
            hv.z = f2bf(acc0[c].z); hv.w = f2bf(acc0[c].w);
            h4[(size_t)n0 * 16 + fg * 4 + c] = hv;
        }
    }
    if (v1) {
        #pragma unroll
        for (int c = 0; c < 4; ++c) {
            ushort4 hv;
            hv.x = f2bf(acc1[c].x); hv.y = f2bf(acc1[c].y);
            hv.z = f2bf(acc1[c].z); hv.w = f2bf(acc1[c].w);
            h4[(size_t)n1 * 16 + fg * 4 + c] = hv;
        }
    }
}

// ---------------------------------------------------------------------------
// Partition v2: (bucket, rank) known at histogram time -> write ebuf slot
// DIRECTLY. Round-6's 512-wide scan + 16KB restage + 9-step serial LDS binary
// search per edge (the dominant dependent-latency chain) are deleted.
// Edge packed to 4B: src (17b) | dst_local (8b) << 17.
// ---------------------------------------------------------------------------
__global__ __launch_bounds__(256) void partition_kernel(const int* __restrict__ ei,
                                                        int* __restrict__ gcur,
                                                        int* __restrict__ ebuf) {
    __shared__ int cnt[512];
    __shared__ int gbase[512];

    const int tid = threadIdx.x;
    cnt[tid] = 0; cnt[tid + 256] = 0;
    __syncthreads();

    const int e0   = blockIdx.x * EPB;
    const int ecnt = min(EPB, N_EDGES - e0);

    int pk[16], meta[16];
    #pragma unroll
    for (int i = 0; i < 16; ++i) {
        const int l = tid + i * 256;
        meta[i] = -1;
        if (l < ecnt) {
            const int e   = e0 + l;
            const int src = ei[e];
            const int dst = ei[N_EDGES + e];
            const int b   = dst / G;
            const int dl  = dst - b * G;
            pk[i] = src | (dl << 17);
            const int r = atomicAdd(&cnt[b], 1);     // LDS atomic
            meta[i] = b | (r << 9);                  // b:9b, r<4096:12b
        }
    }
    __syncthreads();

    for (int b = tid; b < NBKT; b += 256) {
        const int c = cnt[b];
        if (c > 0) gbase[b] = atomicAdd(&gcur[b], c);  // 1 dev atomic/bucket
    }
    __syncthreads();

    #pragma unroll
    for (int i = 0; i < 16; ++i) {
        if (meta[i] >= 0) {
            const int b   = meta[i] & 511;
            const int pos = gbase[b] + (meta[i] >> 9);
            if (pos < CAP) ebuf[(size_t)b * CAP + pos] = pk[i];
        }
    }
}

// ---------------------------------------------------------------------------
// Accumulate v4: 2 blocks/bucket (512 thr). Local CSR in LDS, then gather:
// lane = (edge-sub 0..3) x (f4 0..15); h rows are bf16 (128B) -> ushort4/lane;
// 4 rows per load-group, 16-stride unroll = 4 loads in flight; fp32 register
// acc; shfl_xor reduce; fused bias+relu store.
// ---------------------------------------------------------------------------
__global__ __launch_bounds__(512) void accumulate_kernel(const unsigned short* __restrict__ hb,
                                                         const int* __restrict__ gcur,
                                                         const int* __restrict__ ebuf,
                                                         const float* __restrict__ bias,
                                                         float* __restrict__ out) {
    __shared__ int srt[CAP];        // 24 KB
    __shared__ int cnt[256];
    __shared__ int scanb[256];
    __shared__ int start[G + 1];

    const int b   = blockIdx.x >> 1;
    const int p   = blockIdx.x & 1;
    const int tid = threadIdx.x;
    const int ecnt = min(gcur[b], CAP);

    if (tid < 256) cnt[tid] = 0;
    __syncthreads();

    int pk[8], rr[8];
    #pragma unroll
    for (int i = 0; i < 8; ++i) {
        const int idx = tid + i * 512;
        rr[i] = -1;
        if (idx < ecnt) {
            pk[i] = ebuf[(size_t)b * CAP + idx];
            rr[i] = atomicAdd(&cnt[pk[i] >> 17], 1);
        }
    }
    __syncthreads();

    if (tid < 256) scanb[tid] = cnt[tid];
    __syncthreads();
    for (int off = 1; off < 256; off <<= 1) {
        int v = 0;
        if (tid < 256 && tid >= off) v = scanb[tid - off];
        __syncthreads();
        if (tid < 256) scanb[tid] += v;
        __syncthreads();
    }
    if (tid <= G) start[tid] = (tid == 0) ? 0 : scanb[tid - 1];
    __syncthreads();

    #pragma unroll
    for (int i = 0; i < 8; ++i) {
        if (rr[i] >= 0) {
            const int dl = pk[i] >> 17;
            srt[start[dl] + rr[i]] = pk[i] & 0x1FFFF;
        }
    }
    __syncthreads();

    const int wave = tid >> 6;
    const int lane = tid & 63;
    const int sub  = lane >> 4;
    const int f4   = lane & 15;
    const ushort4* h4 = reinterpret_cast<const ushort4*>(hb);
    const float4 bv   = reinterpret_cast<const float4*>(bias)[f4];
    float4* o4 = reinterpret_cast<float4*>(out);

    const int r0 = p * (G / 2);
    for (int r = r0 + wave; r < r0 + G / 2; r += 8) {
        const int node = b * G + r;
        if (node >= N_NODES) break;
        const int s = start[r];
        const int e = start[r + 1];
        float4 acc = make_float4(0.f, 0.f, 0.f, 0.f);
        int j = s + sub;
        for (; j + 12 < e; j += 16) {
            const int s0 = srt[j], s1 = srt[j + 4], s2 = srt[j + 8], s3 = srt[j + 12];
            const ushort4 a0 = h4[(size_t)s0 * 16 + f4];
            const ushort4 a1 = h4[(size_t)s1 * 16 + f4];
            const ushort4 a2 = h4[(size_t)s2 * 16 + f4];
            const ushort4 a3 = h4[(size_t)s3 * 16 + f4];
            acc.x += bf2f(a0.x) + bf2f(a1.x) + bf2f(a2.x) + bf2f(a3.x);
            acc.y += bf2f(a0.y) + bf2f(a1.y) + bf2f(a2.y) + bf2f(a3.y);
            acc.z += bf2f(a0.z) + bf2f(a1.z) + bf2f(a2.z) + bf2f(a3.z);
            acc.w += bf2f(a0.w) + bf2f(a1.w) + bf2f(a2.w) + bf2f(a3.w);
        }
        for (; j < e; j += 4) {
            const ushort4 a = h4[(size_t)srt[j] * 16 + f4];
            acc.x += bf2f(a.x); acc.y += bf2f(a.y);
            acc.z += bf2f(a.z); acc.w += bf2f(a.w);
        }
        #pragma unroll
        for (int m = 16; m <= 32; m <<= 1) {
            acc.x += __shfl_xor(acc.x, m, 64);
            acc.y += __shfl_xor(acc.y, m, 64);
            acc.z += __shfl_xor(acc.z, m, 64);
            acc.w += __shfl_xor(acc.w, m, 64);
        }
        if (sub == 0) {
            float4 o;
            o.x = fmaxf(acc.x + bv.x, 0.f);
            o.y = fmaxf(acc.y + bv.y, 0.f);
            o.z = fmaxf(acc.z + bv.z, 0.f);
            o.w = fmaxf(acc.w + bv.w, 0.f);
            o4[(size_t)node * 16 + f4] = o;
        }
    }
}

// ---------------------------------------------------------------------------
// Fallback path (atomic scatter on bf16 h) if ws too small
// ---------------------------------------------------------------------------
__global__ void init_bias_kernel(float* __restrict__ out, const float* __restrict__ b) {
    int i = blockIdx.x * blockDim.x + threadIdx.x;
    const int total4 = N_NODES * (D_OUT / 4);
    if (i < total4) {
        int f4 = i & (D_OUT / 4 - 1);
        reinterpret_cast<float4*>(out)[i] = reinterpret_cast<const float4*>(b)[f4];
    }
}

__global__ void scatter_kernel(const unsigned short* __restrict__ hb, const int* __restrict__ ei,
                               float* __restrict__ out) {
    const long long t = (long long)blockIdx.x * blockDim.x + threadIdx.x;
    const int e = (int)(t >> 6);
    const int f = (int)(t & 63);
    if (e < N_EDGES) {
        atomicAdd(out + (size_t)ei[N_EDGES + e] * D_OUT + f,
                  bf2f(hb[(size_t)ei[e] * D_OUT + f]));
    }
}

__global__ void relu_kernel(float* __restrict__ out) {
    int i = blockIdx.x * blockDim.x + threadIdx.x;
    const int total4 = N_NODES * (D_OUT / 4);
    if (i < total4) {
        float4 v = reinterpret_cast<float4*>(out)[i];
        v.x = fmaxf(v.x, 0.f); v.y = fmaxf(v.y, 0.f);
        v.z = fmaxf(v.z, 0.f); v.w = fmaxf(v.w, 0.f);
        reinterpret_cast<float4*>(out)[i] = v;
    }
}

// ---------------------------------------------------------------------------
extern "C" void kernel_launch(void* const* d_in, const int* in_sizes, int n_in,
                              void* d_out, int out_size, void* d_ws, size_t ws_size,
                              hipStream_t stream) {
    const float* x  = (const float*)d_in[0];
    const int*   ei = (const int*)d_in[1];
    const float* W  = (const float*)d_in[2];
    const float* b  = (const float*)d_in[3];
    float* out = (float*)d_out;
    char*  ws  = (char*)d_ws;

    size_t off = 0;
    auto take = [&](size_t bytes) { size_t p = off; off = (off + bytes + 255) & ~255ULL; return p; };
    const size_t o_h    = take((size_t)N_NODES * D_OUT * sizeof(unsigned short)); // 12.8 MB
    const size_t o_gcur = take((size_t)NBKT * sizeof(int));
    const size_t o_ebuf = take((size_t)NBKT * CAP * sizeof(int));                 // 10.25 MB
    const size_t needed = off;

    unsigned short* hb = (unsigned short*)(ws + o_h);

    gemm_kernel<<<(N_NODES + 127) / 128, 256, 0, stream>>>(x, W, hb);

    if (needed <= ws_size) {
        int* gcur = (int*)(ws + o_gcur);
        int* ebuf = (int*)(ws + o_ebuf);
        hipMemsetAsync(gcur, 0, (size_t)NBKT * sizeof(int), stream);
        partition_kernel<<<PBLK, 256, 0, stream>>>(ei, gcur, ebuf);
        accumulate_kernel<<<NBKT * 2, 512, 0, stream>>>(hb, gcur, ebuf, b, out);
    } else {
        const int total4 = N_NODES * (D_OUT / 4);
        init_bias_kernel<<<(total4 + 255) / 256, 256, 0, stream>>>(out, b);
        const long long threads = (long long)N_EDGES * 64;
        scatter_kernel<<<(int)((threads + 255) / 256), 256, 0, stream>>>(hb, ei, out);
        relu_kernel<<<(total4 + 255) / 256, 256, 0, stream>>>(out);
    }
}

// Round 8
// 181.245 us; speedup vs baseline: 4.6342x; 1.0577x over previous
//
#include <hip/hip_runtime.h>

#define N_NODES 100000
#define N_EDGES 1600000
#define D_IN    128
#define D_OUT   64

// Bucket scheme: nodes grouped into buckets of G; per-bucket edge lists with
// fixed capacity CAP (avg fill 3840, binomial sd ~62 -> 6144 is ~37 sigma).
#define G     240
#define NBKT  ((N_NODES + G - 1) / G)          // 417
#define CAP   6144
#define EPB   4096                              // edges per partition block
#define PBLK  ((N_EDGES + EPB - 1) / EPB)       // 391

typedef __attribute__((ext_vector_type(8))) short bf16x8;
typedef __attribute__((ext_vector_type(4))) float f32x4;

// fp32 <-> bf16 helpers (RNE)
__device__ __forceinline__ unsigned short f2bf(float f) {
    union { float f; unsigned u; } v; v.f = f;
    const unsigned r = v.u + 0x7FFFu + ((v.u >> 16) & 1u);
    return (unsigned short)(r >> 16);
}
__device__ __forceinline__ float bf2f(unsigned short s) {
    union { unsigned u; float f; } v; v.u = ((unsigned)s) << 16;
    return v.f;
}

// ---------------------------------------------------------------------------
// gemm v2: bf16 MFMA. Block = 4 waves x 16 nodes = 64 nodes; grid 1563.
// W staged TRANSPOSED bf16 in LDS (Wt[f][k], 16 KB) -> each B-frag is one
// 16B contiguous ds_read. x rows read fp32 (32B/lane per K-step), cvt to
// bf16 in-reg. 16 MFMA per wave covers 16 nodes x 64 feats x K=128.
// Layouts (guide section 3, HW-verified): A[m=lane&15][k=quad*8+j],
// B[k=quad*8+j][n=lane&15], C/D col=lane&15 row=quad*4+reg.
// Replaces the fp32 vector gemm whose 1.6 GB of per-FMA LDS reads +
// 12us-issue/52us-wall latency bind capped it at 52 us.
// ---------------------------------------------------------------------------
__global__ __launch_bounds__(256) void gemm_kernel(const float* __restrict__ x,
                                                   const float* __restrict__ W,
                                                   unsigned short* __restrict__ hb) {
    __shared__ unsigned short Wt[D_OUT * D_IN];   // [f][k] bf16, 16 KB
    const int tid = threadIdx.x;
    for (int i = tid; i < D_IN * D_OUT; i += 256) {
        const int k = i >> 6;                      // W is [k][f] row-major
        const int f = i & 63;
        Wt[f * D_IN + k] = f2bf(W[i]);
    }
    __syncthreads();

    const int wave = tid >> 6;
    const int lane = tid & 63;
    const int m    = lane & 15;
    const int quad = lane >> 4;
    const int n0   = blockIdx.x * 64 + wave * 16;

    // B fragments: [feat-tile][K-step], one ds_read_b128 each
    bf16x8 bfrag[4][4];
    #pragma unroll
    for (int ft = 0; ft < 4; ++ft)
        #pragma unroll
        for (int ks = 0; ks < 4; ++ks)
            bfrag[ft][ks] = *reinterpret_cast<const bf16x8*>(
                &Wt[(ft * 16 + m) * D_IN + ks * 32 + quad * 8]);

    // A fragments: lane m's x row, 8 contiguous k per K-step (clamped at tail)
    const int nodeA = min(n0 + m, N_NODES - 1);
    const float* xr = x + (size_t)nodeA * D_IN;
    bf16x8 afrag[4];
    #pragma unroll
    for (int ks = 0; ks < 4; ++ks) {
        const float4 u = *reinterpret_cast<const float4*>(xr + ks * 32 + quad * 8);
        const float4 v = *reinterpret_cast<const float4*>(xr + ks * 32 + quad * 8 + 4);
        bf16x8 a;
        a[0] = (short)f2bf(u.x); a[1] = (short)f2bf(u.y);
        a[2] = (short)f2bf(u.z); a[3] = (short)f2bf(u.w);
        a[4] = (short)f2bf(v.x); a[5] = (short)f2bf(v.y);
        a[6] = (short)f2bf(v.z); a[7] = (short)f2bf(v.w);
        afrag[ks] = a;
    }

    f32x4 acc[4];
    #pragma unroll
    for (int ft = 0; ft < 4; ++ft) { acc[ft][0]=0.f; acc[ft][1]=0.f; acc[ft][2]=0.f; acc[ft][3]=0.f; }

    #pragma unroll
    for (int ks = 0; ks < 4; ++ks)
        #pragma unroll
        for (int ft = 0; ft < 4; ++ft)
            acc[ft] = __builtin_amdgcn_mfma_f32_16x16x32_bf16(
                afrag[ks], bfrag[ft][ks], acc[ft], 0, 0, 0);

    // D: row = quad*4 + r (node), col = m (feature within tile)
    #pragma unroll
    for (int r = 0; r < 4; ++r) {
        const int node = n0 + quad * 4 + r;
        if (node < N_NODES) {
            #pragma unroll
            for (int ft = 0; ft < 4; ++ft)
                hb[(size_t)node * D_OUT + ft * 16 + m] = f2bf(acc[ft][r]);
        }
    }
}

// ---------------------------------------------------------------------------
// Partition v3: hist -> scan -> restage (bucket-grouped) -> coalesced-run
// writeout. The global slot of each stage index is PRECOMPUTED into gdst[]
// at restage time (b, r, gbase known) -- no binary search (v1's serial
// chain), no per-lane scattered stores (v2's ~90us line-rate bind).
// Edge packed to 4B: src (17b) | dst_local (8b) << 17.
// ---------------------------------------------------------------------------
__global__ __launch_bounds__(256) void partition_kernel(const int* __restrict__ ei,
                                                        int* __restrict__ gcur,
                                                        int* __restrict__ ebuf) {
    __shared__ int cnt[512];
    __shared__ int sA[512];       // inclusive scan of cnt
    __shared__ int gbase[512];
    __shared__ int stage[EPB];    // 16 KB
    __shared__ int gdst[EPB];     // 16 KB

    const int tid = threadIdx.x;
    cnt[tid] = 0; cnt[tid + 256] = 0;
    __syncthreads();

    const int e0   = blockIdx.x * EPB;
    const int ecnt = min(EPB, N_EDGES - e0);

    int pk[16], meta[16];
    #pragma unroll
    for (int i = 0; i < 16; ++i) {
        const int l = tid + i * 256;
        meta[i] = -1;
        if (l < ecnt) {
            const int e   = e0 + l;
            const int src = ei[e];
            const int dst = ei[N_EDGES + e];
            const int b   = dst / G;
            const int dl  = dst - b * G;
            pk[i] = src | (dl << 17);
            const int r = atomicAdd(&cnt[b], 1);   // LDS atomic
            meta[i] = b | (r << 9);                // b:9b, r:12b
        }
    }
    __syncthreads();

    sA[tid] = cnt[tid]; sA[tid + 256] = cnt[tid + 256];
    __syncthreads();
    for (int off = 1; off < 512; off <<= 1) {
        const int a0 = (tid >= off) ? sA[tid - off] : 0;
        const int a1 = sA[tid + 256 - off];
        __syncthreads();
        sA[tid] += a0; sA[tid + 256] += a1;
        __syncthreads();
    }

    for (int b = tid; b < NBKT; b += 256) {
        const int c = cnt[b];
        if (c > 0) gbase[b] = atomicAdd(&gcur[b], c);  // 1 dev atomic/bucket
    }
    __syncthreads();

    // restage bucket-grouped; precompute global destination per slot
    #pragma unroll
    for (int i = 0; i < 16; ++i) {
        if (meta[i] >= 0) {
            const int b    = meta[i] & 511;
            const int r    = meta[i] >> 9;
            const int spos = (sA[b] - cnt[b]) + r;
            const int g    = gbase[b] + r;
            stage[spos] = pk[i];
            gdst[spos]  = (g < CAP) ? b * CAP + g : -1;
        }
    }
    __syncthreads();

    // writeout: consecutive idx -> consecutive global addresses within runs
    #pragma unroll
    for (int i = 0; i < 16; ++i) {
        const int idx = tid + i * 256;
        if (idx < ecnt) {
            const int pos = gdst[idx];
            if (pos >= 0) ebuf[pos] = stage[idx];
        }
    }
}

// ---------------------------------------------------------------------------
// Accumulate v4 (unchanged): 2 blocks/bucket, local CSR in LDS, multi-row
// bf16 gather (4 rows/load-group, 4 groups in flight), fp32 register acc,
// shfl_xor reduce, fused bias+relu.
// ---------------------------------------------------------------------------
__global__ __launch_bounds__(512) void accumulate_kernel(const unsigned short* __restrict__ hb,
                                                         const int* __restrict__ gcur,
                                                         const int* __restrict__ ebuf,
                                                         const float* __restrict__ bias,
                                                         float* __restrict__ out) {
    __shared__ int srt[CAP];        // 24 KB
    __shared__ int cnt[256];
    __shared__ int scanb[256];
    __shared__ int start[G + 1];

    const int b   = blockIdx.x >> 1;
    const int p   = blockIdx.x & 1;
    const int tid = threadIdx.x;
    const int ecnt = min(gcur[b], CAP);

    if (tid < 256) cnt[tid] = 0;
    __syncthreads();

    int pk[8], rr[8];
    #pragma unroll
    for (int i = 0; i < 8; ++i) {
        const int idx = tid + i * 512;
        rr[i] = -1;
        if (idx < ecnt) {
            pk[i] = ebuf[(size_t)b * CAP + idx];
            rr[i] = atomicAdd(&cnt[pk[i] >> 17], 1);
        }
    }
    __syncthreads();

    if (tid < 256) scanb[tid] = cnt[tid];
    __syncthreads();
    for (int off = 1; off < 256; off <<= 1) {
        int v = 0;
        if (tid < 256 && tid >= off) v = scanb[tid - off];
        __syncthreads();
        if (tid < 256) scanb[tid] += v;
        __syncthreads();
    }
    if (tid <= G) start[tid] = (tid == 0) ? 0 : scanb[tid - 1];
    __syncthreads();

    #pragma unroll
    for (int i = 0; i < 8; ++i) {
        if (rr[i] >= 0) {
            const int dl = pk[i] >> 17;
            srt[start[dl] + rr[i]] = pk[i] & 0x1FFFF;
        }
    }
    __syncthreads();

    const int wave = tid >> 6;
    const int lane = tid & 63;
    const int sub  = lane >> 4;
    const int f4   = lane & 15;
    const ushort4* h4 = reinterpret_cast<const ushort4*>(hb);
    const float4 bv   = reinterpret_cast<const float4*>(bias)[f4];
    float4* o4 = reinterpret_cast<float4*>(out);

    const int r0 = p * (G / 2);
    for (int r = r0 + wave; r < r0 + G / 2; r += 8) {
        const int node = b * G + r;
        if (node >= N_NODES) break;
        const int s = start[r];
        const int e = start[r + 1];
        float4 acc = make_float4(0.f, 0.f, 0.f, 0.f);
        int j = s + sub;
        for (; j + 12 < e; j += 16) {
            const int s0 = srt[j], s1 = srt[j + 4], s2 = srt[j + 8], s3 = srt[j + 12];
            const ushort4 a0 = h4[(size_t)s0 * 16 + f4];
            const ushort4 a1 = h4[(size_t)s1 * 16 + f4];
            const ushort4 a2 = h4[(size_t)s2 * 16 + f4];
            const ushort4 a3 = h4[(size_t)s3 * 16 + f4];
            acc.x += bf2f(a0.x) + bf2f(a1.x) + bf2f(a2.x) + bf2f(a3.x);
            acc.y += bf2f(a0.y) + bf2f(a1.y) + bf2f(a2.y) + bf2f(a3.y);
            acc.z += bf2f(a0.z) + bf2f(a1.z) + bf2f(a2.z) + bf2f(a3.z);
            acc.w += bf2f(a0.w) + bf2f(a1.w) + bf2f(a2.w) + bf2f(a3.w);
        }
        for (; j < e; j += 4) {
            const ushort4 a = h4[(size_t)srt[j] * 16 + f4];
            acc.x += bf2f(a.x); acc.y += bf2f(a.y);
            acc.z += bf2f(a.z); acc.w += bf2f(a.w);
        }
        #pragma unroll
        for (int mm = 16; mm <= 32; mm <<= 1) {
            acc.x += __shfl_xor(acc.x, mm, 64);
            acc.y += __shfl_xor(acc.y, mm, 64);
            acc.z += __shfl_xor(acc.z, mm, 64);
            acc.w += __shfl_xor(acc.w, mm, 64);
        }
        if (sub == 0) {
            float4 o;
            o.x = fmaxf(acc.x + bv.x, 0.f);
            o.y = fmaxf(acc.y + bv.y, 0.f);
            o.z = fmaxf(acc.z + bv.z, 0.f);
            o.w = fmaxf(acc.w + bv.w, 0.f);
            o4[(size_t)node * 16 + f4] = o;
        }
    }
}

// ---------------------------------------------------------------------------
// Fallback path (atomic scatter on bf16 h) if ws too small
// ---------------------------------------------------------------------------
__global__ void init_bias_kernel(float* __restrict__ out, const float* __restrict__ b) {
    int i = blockIdx.x * blockDim.x + threadIdx.x;
    const int total4 = N_NODES * (D_OUT / 4);
    if (i < total4) {
        int f4 = i & (D_OUT / 4 - 1);
        reinterpret_cast<float4*>(out)[i] = reinterpret_cast<const float4*>(b)[f4];
    }
}

__global__ void scatter_kernel(const unsigned short* __restrict__ hb, const int* __restrict__ ei,
                               float* __restrict__ out) {
    const long long t = (long long)blockIdx.x * blockDim.x + threadIdx.x;
    const int e = (int)(t >> 6);
    const int f = (int)(t & 63);
    if (e < N_EDGES) {
        atomicAdd(out + (size_t)ei[N_EDGES + e] * D_OUT + f,
                  bf2f(hb[(size_t)ei[e] * D_OUT + f]));
    }
}

__global__ void relu_kernel(float* __restrict__ out) {
    int i = blockIdx.x * blockDim.x + threadIdx.x;
    const int total4 = N_NODES * (D_OUT / 4);
    if (i < total4) {
        float4 v = reinterpret_cast<float4*>(out)[i];
        v.x = fmaxf(v.x, 0.f); v.y = fmaxf(v.y, 0.f);
        v.z = fmaxf(v.z, 0.f); v.w = fmaxf(v.w, 0.f);
        reinterpret_cast<float4*>(out)[i] = v;
    }
}

// ---------------------------------------------------------------------------
extern "C" void kernel_launch(void* const* d_in, const int* in_sizes, int n_in,
                              void* d_out, int out_size, void* d_ws, size_t ws_size,
                              hipStream_t stream) {
    const float* x  = (const float*)d_in[0];
    const int*   ei = (const int*)d_in[1];
    const float* W  = (const float*)d_in[2];
    const float* b  = (const float*)d_in[3];
    float* out = (float*)d_out;
    char*  ws  = (char*)d_ws;

    size_t off = 0;
    auto take = [&](size_t bytes) { size_t p = off; off = (off + bytes + 255) & ~255ULL; return p; };
    const size_t o_h    = take((size_t)N_NODES * D_OUT * sizeof(unsigned short)); // 12.8 MB
    const size_t o_gcur = take((size_t)NBKT * sizeof(int));
    const size_t o_ebuf = take((size_t)NBKT * CAP * sizeof(int));                 // 10.25 MB
    const size_t needed = off;

    unsigned short* hb = (unsigned short*)(ws + o_h);

    gemm_kernel<<<(N_NODES + 63) / 64, 256, 0, stream>>>(x, W, hb);

    if (needed <= ws_size) {
        int* gcur = (int*)(ws + o_gcur);
        int* ebuf = (int*)(ws + o_ebuf);
        hipMemsetAsync(gcur, 0, (size_t)NBKT * sizeof(int), stream);
        partition_kernel<<<PBLK, 256, 0, stream>>>(ei, gcur, ebuf);
        accumulate_kernel<<<NBKT * 2, 512, 0, stream>>>(hb, gcur, ebuf, b, out);
    } else {
        const int total4 = N_NODES * (D_OUT / 4);
        init_bias_kernel<<<(total4 + 255) / 256, 256, 0, stream>>>(out, b);
        const long long threads = (long long)N_EDGES * 64;
        scatter_kernel<<<(int)((threads + 255) / 256), 256, 0, stream>>>(hb, ei, out);
        relu_kernel<<<(total4 + 255) / 256, 256, 0, stream>>>(out);
    }
}

// Round 9
// 164.834 us; speedup vs baseline: 5.0955x; 1.0996x over previous
//
#include <hip/hip_runtime.h>

#define N_NODES 100000
#define N_EDGES 1600000
#define D_IN    128
#define D_OUT   64

// Bucket scheme: nodes grouped into buckets of G; per-bucket edge lists with
// fixed capacity CAP (avg fill 3840, binomial sd ~62 -> 6144 is ~37 sigma).
#define G     240
#define NBKT  ((N_NODES + G - 1) / G)          // 417
#define CAP   6144
#define EPB   4096                              // edges per partition block
#define PBLK  ((N_EDGES + EPB - 1) / EPB)       // 391
#define GBLK  ((N_NODES + 63) / 64)             // 1563 gemm blocks

typedef __attribute__((ext_vector_type(8))) short bf16x8;
typedef __attribute__((ext_vector_type(4))) float f32x4;

// fp32 <-> bf16 helpers (RNE)
__device__ __forceinline__ unsigned short f2bf(float f) {
    union { float f; unsigned u; } v; v.f = f;
    const unsigned r = v.u + 0x7FFFu + ((v.u >> 16) & 1u);
    return (unsigned short)(r >> 16);
}
__device__ __forceinline__ float bf2f(unsigned short s) {
    union { unsigned u; float f; } v; v.u = ((unsigned)s) << 16;
    return v.f;
}

// ---------------------------------------------------------------------------
// Fused gemm + partition. The two phases are data-independent (gemm: x,W->hb;
// partition: ei->ebuf) and bound by disjoint resources (gemm: HBM/MFMA;
// partition: LDS atomics + barriers, 0.3% VALU) -- fusing as block ranges
// overlaps them on the 256 CUs instead of serializing two dispatches.
// Blocks [0,PBLK): partition. Blocks [PBLK, PBLK+GBLK): gemm.
// Shared LDS union: partition 38.9 KB | gemm Wt 16 KB -> 4 blocks/CU.
// ---------------------------------------------------------------------------
__global__ __launch_bounds__(256) void fused_gp_kernel(const float* __restrict__ x,
                                                       const float* __restrict__ W,
                                                       unsigned short* __restrict__ hb,
                                                       const int* __restrict__ ei,
                                                       int* __restrict__ gcur,
                                                       int* __restrict__ ebuf) {
    __shared__ int smem[1536 + 2 * EPB];   // 38912 B

    const int tid = threadIdx.x;

    if (blockIdx.x < PBLK) {
        // ----------------- partition path (v3: restage + precomputed gdst) --
        int* cnt   = smem;            // [512]
        int* sA    = smem + 512;      // [512]
        int* gbase = smem + 1024;     // [512]
        int* stage = smem + 1536;     // [EPB]
        int* gdst  = smem + 1536 + EPB;

        cnt[tid] = 0; cnt[tid + 256] = 0;
        __syncthreads();

        const int e0   = blockIdx.x * EPB;
        const int ecnt = min(EPB, N_EDGES - e0);

        int pk[16], meta[16];
        #pragma unroll
        for (int i = 0; i < 16; ++i) {
            const int l = tid + i * 256;
            meta[i] = -1;
            if (l < ecnt) {
                const int e   = e0 + l;
                const int src = ei[e];
                const int dst = ei[N_EDGES + e];
                const int b   = dst / G;
                const int dl  = dst - b * G;
                pk[i] = src | (dl << 17);
                const int r = atomicAdd(&cnt[b], 1);   // LDS atomic
                meta[i] = b | (r << 9);                // b:9b, r:12b
            }
        }
        __syncthreads();

        sA[tid] = cnt[tid]; sA[tid + 256] = cnt[tid + 256];
        __syncthreads();
        for (int off = 1; off < 512; off <<= 1) {
            const int a0 = (tid >= off) ? sA[tid - off] : 0;
            const int a1 = sA[tid + 256 - off];
            __syncthreads();
            sA[tid] += a0; sA[tid + 256] += a1;
            __syncthreads();
        }

        for (int b = tid; b < NBKT; b += 256) {
            const int c = cnt[b];
            if (c > 0) gbase[b] = atomicAdd(&gcur[b], c);  // 1 dev atomic/bkt
        }
        __syncthreads();

        #pragma unroll
        for (int i = 0; i < 16; ++i) {
            if (meta[i] >= 0) {
                const int b    = meta[i] & 511;
                const int r    = meta[i] >> 9;
                const int spos = (sA[b] - cnt[b]) + r;
                const int g    = gbase[b] + r;
                stage[spos] = pk[i];
                gdst[spos]  = (g < CAP) ? b * CAP + g : -1;
            }
        }
        __syncthreads();

        #pragma unroll
        for (int i = 0; i < 16; ++i) {
            const int idx = tid + i * 256;
            if (idx < ecnt) {
                const int pos = gdst[idx];
                if (pos >= 0) ebuf[pos] = stage[idx];
            }
        }
    } else {
        // ----------------- gemm path (bf16 MFMA, W^T staged in LDS) ---------
        unsigned short* Wt = reinterpret_cast<unsigned short*>(smem); // 16 KB
        for (int i = tid; i < D_IN * D_OUT; i += 256) {
            const int k = i >> 6;                      // W is [k][f] row-major
            const int f = i & 63;
            Wt[f * D_IN + k] = f2bf(W[i]);
        }
        __syncthreads();

        const int wave = tid >> 6;
        const int lane = tid & 63;
        const int m    = lane & 15;
        const int quad = lane >> 4;
        const int n0   = (blockIdx.x - PBLK) * 64 + wave * 16;

        bf16x8 bfrag[4][4];
        #pragma unroll
        for (int ft = 0; ft < 4; ++ft)
            #pragma unroll
            for (int ks = 0; ks < 4; ++ks)
                bfrag[ft][ks] = *reinterpret_cast<const bf16x8*>(
                    &Wt[(ft * 16 + m) * D_IN + ks * 32 + quad * 8]);

        const int nodeA = min(n0 + m, N_NODES - 1);
        const float* xr = x + (size_t)nodeA * D_IN;
        bf16x8 afrag[4];
        #pragma unroll
        for (int ks = 0; ks < 4; ++ks) {
            const float4 u = *reinterpret_cast<const float4*>(xr + ks * 32 + quad * 8);
            const float4 v = *reinterpret_cast<const float4*>(xr + ks * 32 + quad * 8 + 4);
            bf16x8 a;
            a[0] = (short)f2bf(u.x); a[1] = (short)f2bf(u.y);
            a[2] = (short)f2bf(u.z); a[3] = (short)f2bf(u.w);
            a[4] = (short)f2bf(v.x); a[5] = (short)f2bf(v.y);
            a[6] = (short)f2bf(v.z); a[7] = (short)f2bf(v.w);
            afrag[ks] = a;
        }

        f32x4 acc[4];
        #pragma unroll
        for (int ft = 0; ft < 4; ++ft) { acc[ft][0]=0.f; acc[ft][1]=0.f; acc[ft][2]=0.f; acc[ft][3]=0.f; }

        #pragma unroll
        for (int ks = 0; ks < 4; ++ks)
            #pragma unroll
            for (int ft = 0; ft < 4; ++ft)
                acc[ft] = __builtin_amdgcn_mfma_f32_16x16x32_bf16(
                    afrag[ks], bfrag[ft][ks], acc[ft], 0, 0, 0);

        #pragma unroll
        for (int r = 0; r < 4; ++r) {
            const int node = n0 + quad * 4 + r;
            if (node < N_NODES) {
                #pragma unroll
                for (int ft = 0; ft < 4; ++ft)
                    hb[(size_t)node * D_OUT + ft * 16 + m] = f2bf(acc[ft][r]);
            }
        }
    }
}

// ---------------------------------------------------------------------------
// Accumulate v4: 2 blocks/bucket, local CSR in LDS, multi-row bf16 gather
// (4 rows/load-group, 4 groups in flight), fp32 register acc, shfl_xor
// reduce, fused bias+relu.
// ---------------------------------------------------------------------------
__global__ __launch_bounds__(512) void accumulate_kernel(const unsigned short* __restrict__ hb,
                                                         const int* __restrict__ gcur,
                                                         const int* __restrict__ ebuf,
                                                         const float* __restrict__ bias,
                                                         float* __restrict__ out) {
    __shared__ int srt[CAP];        // 24 KB
    __shared__ int cnt[256];
    __shared__ int scanb[256];
    __shared__ int start[G + 1];

    const int b   = blockIdx.x >> 1;
    const int p   = blockIdx.x & 1;
    const int tid = threadIdx.x;
    const int ecnt = min(gcur[b], CAP);

    if (tid < 256) cnt[tid] = 0;
    __syncthreads();

    int pk[8], rr[8];
    #pragma unroll
    for (int i = 0; i < 8; ++i) {
        const int idx = tid + i * 512;
        rr[i] = -1;
        if (idx < ecnt) {
            pk[i] = ebuf[(size_t)b * CAP + idx];
            rr[i] = atomicAdd(&cnt[pk[i] >> 17], 1);
        }
    }
    __syncthreads();

    if (tid < 256) scanb[tid] = cnt[tid];
    __syncthreads();
    for (int off = 1; off < 256; off <<= 1) {
        int v = 0;
        if (tid < 256 && tid >= off) v = scanb[tid - off];
        __syncthreads();
        if (tid < 256) scanb[tid] += v;
        __syncthreads();
    }
    if (tid <= G) start[tid] = (tid == 0) ? 0 : scanb[tid - 1];
    __syncthreads();

    #pragma unroll
    for (int i = 0; i < 8; ++i) {
        if (rr[i] >= 0) {
            const int dl = pk[i] >> 17;
            srt[start[dl] + rr[i]] = pk[i] & 0x1FFFF;
        }
    }
    __syncthreads();

    const int wave = tid >> 6;
    const int lane = tid & 63;
    const int sub  = lane >> 4;
    const int f4   = lane & 15;
    const ushort4* h4 = reinterpret_cast<const ushort4*>(hb);
    const float4 bv   = reinterpret_cast<const float4*>(bias)[f4];
    float4* o4 = reinterpret_cast<float4*>(out);

    const int r0 = p * (G / 2);
    for (int r = r0 + wave; r < r0 + G / 2; r += 8) {
        const int node = b * G + r;
        if (node >= N_NODES) break;
        const int s = start[r];
        const int e = start[r + 1];
        float4 acc = make_float4(0.f, 0.f, 0.f, 0.f);
        int j = s + sub;
        for (; j + 12 < e; j += 16) {
            const int s0 = srt[j], s1 = srt[j + 4], s2 = srt[j + 8], s3 = srt[j + 12];
            const ushort4 a0 = h4[(size_t)s0 * 16 + f4];
            const ushort4 a1 = h4[(size_t)s1 * 16 + f4];
            const ushort4 a2 = h4[(size_t)s2 * 16 + f4];
            const ushort4 a3 = h4[(size_t)s3 * 16 + f4];
            acc.x += bf2f(a0.x) + bf2f(a1.x) + bf2f(a2.x) + bf2f(a3.x);
            acc.y += bf2f(a0.y) + bf2f(a1.y) + bf2f(a2.y) + bf2f(a3.y);
            acc.z += bf2f(a0.z) + bf2f(a1.z) + bf2f(a2.z) + bf2f(a3.z);
            acc.w += bf2f(a0.w) + bf2f(a1.w) + bf2f(a2.w) + bf2f(a3.w);
        }
        for (; j < e; j += 4) {
            const ushort4 a = h4[(size_t)srt[j] * 16 + f4];
            acc.x += bf2f(a.x); acc.y += bf2f(a.y);
            acc.z += bf2f(a.z); acc.w += bf2f(a.w);
        }
        #pragma unroll
        for (int mm = 16; mm <= 32; mm <<= 1) {
            acc.x += __shfl_xor(acc.x, mm, 64);
            acc.y += __shfl_xor(acc.y, mm, 64);
            acc.z += __shfl_xor(acc.z, mm, 64);
            acc.w += __shfl_xor(acc.w, mm, 64);
        }
        if (sub == 0) {
            float4 o;
            o.x = fmaxf(acc.x + bv.x, 0.f);
            o.y = fmaxf(acc.y + bv.y, 0.f);
            o.z = fmaxf(acc.z + bv.z, 0.f);
            o.w = fmaxf(acc.w + bv.w, 0.f);
            o4[(size_t)node * 16 + f4] = o;
        }
    }
}

// ---------------------------------------------------------------------------
// Fallback path (standalone gemm + atomic scatter) if ws too small
// ---------------------------------------------------------------------------
__global__ __launch_bounds__(256) void gemm_fallback_kernel(const float* __restrict__ x,
                                                            const float* __restrict__ W,
                                                            unsigned short* __restrict__ hb) {
    __shared__ unsigned short Wt[D_OUT * D_IN];
    const int tid = threadIdx.x;
    for (int i = tid; i < D_IN * D_OUT; i += 256) {
        const int k = i >> 6;
        const int f = i & 63;
        Wt[f * D_IN + k] = f2bf(W[i]);
    }
    __syncthreads();

    const int wave = tid >> 6;
    const int lane = tid & 63;
    const int m    = lane & 15;
    const int quad = lane >> 4;
    const int n0   = blockIdx.x * 64 + wave * 16;

    bf16x8 bfrag[4][4];
    #pragma unroll
    for (int ft = 0; ft < 4; ++ft)
        #pragma unroll
        for (int ks = 0; ks < 4; ++ks)
            bfrag[ft][ks] = *reinterpret_cast<const bf16x8*>(
                &Wt[(ft * 16 + m) * D_IN + ks * 32 + quad * 8]);

    const int nodeA = min(n0 + m, N_NODES - 1);
    const float* xr = x + (size_t)nodeA * D_IN;
    bf16x8 afrag[4];
    #pragma unroll
    for (int ks = 0; ks < 4; ++ks) {
        const float4 u = *reinterpret_cast<const float4*>(xr + ks * 32 + quad * 8);
        const float4 v = *reinterpret_cast<const float4*>(xr + ks * 32 + quad * 8 + 4);
        bf16x8 a;
        a[0] = (short)f2bf(u.x); a[1] = (short)f2bf(u.y);
        a[2] = (short)f2bf(u.z); a[3] = (short)f2bf(u.w);
        a[4] = (short)f2bf(v.x); a[5] = (short)f2bf(v.y);
        a[6] = (short)f2bf(v.z); a[7] = (short)f2bf(v.w);
        afrag[ks] = a;
    }

    f32x4 acc[4];
    #pragma unroll
    for (int ft = 0; ft < 4; ++ft) { acc[ft][0]=0.f; acc[ft][1]=0.f; acc[ft][2]=0.f; acc[ft][3]=0.f; }

    #pragma unroll
    for (int ks = 0; ks < 4; ++ks)
        #pragma unroll
        for (int ft = 0; ft < 4; ++ft)
            acc[ft] = __builtin_amdgcn_mfma_f32_16x16x32_bf16(
                afrag[ks], bfrag[ft][ks], acc[ft], 0, 0, 0);

    #pragma unroll
    for (int r = 0; r < 4; ++r) {
        const int node = n0 + quad * 4 + r;
        if (node < N_NODES) {
            #pragma unroll
            for (int ft = 0; ft < 4; ++ft)
                hb[(size_t)node * D_OUT + ft * 16 + m] = f2bf(acc[ft][r]);
        }
    }
}

__global__ void init_bias_kernel(float* __restrict__ out, const float* __restrict__ b) {
    int i = blockIdx.x * blockDim.x + threadIdx.x;
    const int total4 = N_NODES * (D_OUT / 4);
    if (i < total4) {
        int f4 = i & (D_OUT / 4 - 1);
        reinterpret_cast<float4*>(out)[i] = reinterpret_cast<const float4*>(b)[f4];
    }
}

__global__ void scatter_kernel(const unsigned short* __restrict__ hb, const int* __restrict__ ei,
                               float* __restrict__ out) {
    const long long t = (long long)blockIdx.x * blockDim.x + threadIdx.x;
    const int e = (int)(t >> 6);
    const int f = (int)(t & 63);
    if (e < N_EDGES) {
        atomicAdd(out + (size_t)ei[N_EDGES + e] * D_OUT + f,
                  bf2f(hb[(size_t)ei[e] * D_OUT + f]));
    }
}

__global__ void relu_kernel(float* __restrict__ out) {
    int i = blockIdx.x * blockDim.x + threadIdx.x;
    const int total4 = N_NODES * (D_OUT / 4);
    if (i < total4) {
        float4 v = reinterpret_cast<float4*>(out)[i];
        v.x = fmaxf(v.x, 0.f); v.y = fmaxf(v.y, 0.f);
        v.z = fmaxf(v.z, 0.f); v.w = fmaxf(v.w, 0.f);
        reinterpret_cast<float4*>(out)[i] = v;
    }
}

// ---------------------------------------------------------------------------
extern "C" void kernel_launch(void* const* d_in, const int* in_sizes, int n_in,
                              void* d_out, int out_size, void* d_ws, size_t ws_size,
                              hipStream_t stream) {
    const float* x  = (const float*)d_in[0];
    const int*   ei = (const int*)d_in[1];
    const float* W  = (const float*)d_in[2];
    const float* b  = (const float*)d_in[3];
    float* out = (float*)d_out;
    char*  ws  = (char*)d_ws;

    size_t off = 0;
    auto take = [&](size_t bytes) { size_t p = off; off = (off + bytes + 255) & ~255ULL; return p; };
    const size_t o_h    = take((size_t)N_NODES * D_OUT * sizeof(unsigned short)); // 12.8 MB
    const size_t o_gcur = take((size_t)NBKT * sizeof(int));
    const size_t o_ebuf = take((size_t)NBKT * CAP * sizeof(int));                 // 10.25 MB
    const size_t needed = off;

    unsigned short* hb = (unsigned short*)(ws + o_h);

    if (needed <= ws_size) {
        int* gcur = (int*)(ws + o_gcur);
        int* ebuf = (int*)(ws + o_ebuf);
        hipMemsetAsync(gcur, 0, (size_t)NBKT * sizeof(int), stream);
        fused_gp_kernel<<<PBLK + GBLK, 256, 0, stream>>>(x, W, hb, ei, gcur, ebuf);
        accumulate_kernel<<<NBKT * 2, 512, 0, stream>>>(hb, gcur, ebuf, b, out);
    } else {
        gemm_fallback_kernel<<<GBLK, 256, 0, stream>>>(x, W, hb);
        const int total4 = N_NODES * (D_OUT / 4);
        init_bias_kernel<<<(total4 + 255) / 256, 256, 0, stream>>>(out, b);
        const long long threads = (long long)N_EDGES * 64;
        scatter_kernel<<<(int)((threads + 255) / 256), 256, 0, stream>>>(hb, ei, out);
        relu_kernel<<<(total4 + 255) / 256, 256, 0, stream>>>(out);
    }
}